// Round 10
// baseline (97.168 us; speedup 1.0000x reference)
//
#include <hip/hip_runtime.h>
#include <stdint.h>

typedef __bf16 bf16x8 __attribute__((ext_vector_type(8)));
typedef float  f32x4  __attribute__((ext_vector_type(4)));

constexpr int NB = 32, TT = 2048, JJ = 512, DD = 256;
constexpr int CTX_ROWS = NB * TT;                 // 65536
constexpr int QUE_ROWS = NB * JJ;                 // 16384
constexpr int ALL_ROWS = CTX_ROWS + QUE_ROWS;     // 81920

// d_ws layout (bytes):
//   ctxb  [0,        33554432)   bf16[32][2048][256]  (ctx * wm)
//   queb  [33554432, 41943040)   bf16[32][512][256]
//   cterm [41943040, 42205184)   f32[32][2048]
//   qterm [42205184, 42270720)   f32[32][512]
constexpr size_t WS_QUEB  = 33554432;
constexpr size_t WS_CTERM = 41943040;
constexpr size_t WS_QTERM = 42205184;
constexpr size_t WS_NEED  = 42270720;

// ================= kernel 1: convert + term dots (R5-proven) ================
__global__ __launch_bounds__(256)
void prep_kernel(const float* __restrict__ ctx, const float* __restrict__ que,
                 const float* __restrict__ wvec,
                 __bf16* __restrict__ ctxb, __bf16* __restrict__ queb,
                 float* __restrict__ cterm, float* __restrict__ qterm)
{
    const int tid  = threadIdx.x;
    const int colg = tid & 31;        // 32 col-groups x 8 f32 = 256
    const int rloc = tid >> 5;        // 8 rows per block
    const int k0   = colg * 8;

    const f32x4 wc0 = *(const f32x4*)(wvec + k0);
    const f32x4 wc1 = *(const f32x4*)(wvec + k0 + 4);
    const f32x4 wq0 = *(const f32x4*)(wvec + DD + k0);
    const f32x4 wq1 = *(const f32x4*)(wvec + DD + k0 + 4);
    const f32x4 wm0 = *(const f32x4*)(wvec + 2 * DD + k0);
    const f32x4 wm1 = *(const f32x4*)(wvec + 2 * DD + k0 + 4);

    for (int r = blockIdx.x * 8 + rloc; r < ALL_ROWS; r += gridDim.x * 8) {
        const bool isC = (r < CTX_ROWS);
        const int  rr  = isC ? r : (r - CTX_ROWS);
        const float* src = (isC ? ctx : que) + (size_t)rr * DD + k0;
        const f32x4 x0 = *(const f32x4*)src;
        const f32x4 x1 = *(const f32x4*)(src + 4);

        const f32x4 wd0 = isC ? wc0 : wq0;
        const f32x4 wd1 = isC ? wc1 : wq1;
        float d = x0[0]*wd0[0] + x0[1]*wd0[1] + x0[2]*wd0[2] + x0[3]*wd0[3]
                + x1[0]*wd1[0] + x1[1]*wd1[1] + x1[2]*wd1[2] + x1[3]*wd1[3];
        d += __shfl_xor(d, 1);  d += __shfl_xor(d, 2);  d += __shfl_xor(d, 4);
        d += __shfl_xor(d, 8);  d += __shfl_xor(d, 16);

        bf16x8 pk;
        #pragma unroll
        for (int j = 0; j < 4; ++j) {
            pk[j]     = (__bf16)(isC ? x0[j] * wm0[j] : x0[j]);
            pk[4 + j] = (__bf16)(isC ? x1[j] * wm1[j] : x1[j]);
        }
        *(bf16x8*)((isC ? ctxb : queb) + (size_t)rr * DD + k0) = pk;
        if (colg == 0) (isC ? cterm : qterm)[rr] = d;
    }
}

// ============ kernel 2: barrier-free direct-global MFMA GEMM ================
// One wave owns a 64x64 output tile. Fragments load straight from global
// (bf16 row-major): lanes (lr,hi) -> row*512B + hi*16B = 16 rows x 64B fully
// used segments. No LDS, no barriers; waves free-run; L1 shares A across the
// block's 4 waves (same m-rows, consecutive n).
__global__ __launch_bounds__(256)
void gemm_kernel(const __bf16* __restrict__ ctxb, const __bf16* __restrict__ queb,
                 const float* __restrict__ cterm, const float* __restrict__ qterm,
                 float* __restrict__ out)
{
    const int l   = threadIdx.x & 63;
    const int w   = threadIdx.x >> 6;

    // XCD swizzle: 2048 blocks -> 256 consecutive ids per XCD (4 whole batches)
    const int pb = blockIdx.x;
    const int id = (pb & 7) * 256 + (pb >> 3);

    // wave-tile id: n fast (waves of a block share m-rows -> L1 A-reuse)
    const int tile = id * 4 + w;              // 0..8191
    const int n0 = (tile & 7) * 64;
    const int m0 = ((tile >> 3) & 31) * 64;
    const int bI = tile >> 8;

    const int lr = l & 15;
    const int hi = l >> 4;

    const __bf16* aB = ctxb + ((size_t)bI * TT + m0 + lr) * DD + hi * 8;
    const __bf16* bB = queb + ((size_t)bI * JJ + n0 + lr) * DD + hi * 8;

    f32x4 acc[4][4];
    #pragma unroll
    for (int m = 0; m < 4; ++m)
        #pragma unroll
        for (int n = 0; n < 4; ++n) acc[m][n] = f32x4{0.f, 0.f, 0.f, 0.f};

    #pragma unroll
    for (int w8 = 0; w8 < 8; ++w8) {          // k-window: k = w8*32 + hi*8 + i
        bf16x8 af[4], bfr[4];
        #pragma unroll
        for (int m = 0; m < 4; ++m)
            af[m] = *(const bf16x8*)(aB + (size_t)(m * 16) * DD + w8 * 32);
        #pragma unroll
        for (int n = 0; n < 4; ++n)
            bfr[n] = *(const bf16x8*)(bB + (size_t)(n * 16) * DD + w8 * 32);

        #pragma unroll
        for (int m = 0; m < 4; ++m)
            #pragma unroll
            for (int n = 0; n < 4; ++n)
                acc[m][n] = __builtin_amdgcn_mfma_f32_16x16x32_bf16(bfr[n], af[m],
                                                                    acc[m][n], 0, 0, 0);
    }

    // epilogue (R7-verified mapping): out[t = m*16+lr][j = n*16+hi*4+q]
    const int jb = hi * 4;
    #pragma unroll
    for (int m = 0; m < 4; ++m) {
        const int rowG = m0 + m * 16 + lr;
        const float cv = cterm[(size_t)bI * TT + rowG];
        float* rowp = out + ((size_t)bI * TT + rowG) * JJ + n0;
        #pragma unroll
        for (int n = 0; n < 4; ++n) {
            const int colL = n * 16 + jb;
            const f32x4 qv = *(const f32x4*)(qterm + (size_t)bI * JJ + n0 + colL);
            const f32x4 v = acc[m][n];
            f32x4 o = {v[0] + cv + qv[0], v[1] + cv + qv[1],
                       v[2] + cv + qv[2], v[3] + cv + qv[3]};
            *(f32x4*)(rowp + colL) = o;
        }
    }
}

// ================= fallback (only if ws too small; correctness-only) ========
__global__ __launch_bounds__(256)
void naive_kernel(const float* __restrict__ ctx, const float* __restrict__ que,
                  const float* __restrict__ wvec, float* __restrict__ out)
{
    const int j = blockIdx.x * 16 + (threadIdx.x & 15);
    const int t = blockIdx.y * 16 + (threadIdx.x >> 4);
    const int b = blockIdx.z;
    const float* cr = ctx + ((size_t)b * TT + t) * DD;
    const float* qr = que + ((size_t)b * JJ + j) * DD;
    float s = 0.f, ct = 0.f, qt = 0.f;
    for (int k = 0; k < DD; ++k) {
        const float cv = cr[k], qv = qr[k];
        s  += cv * wvec[2 * DD + k] * qv;
        ct += cv * wvec[k];
        qt += qv * wvec[DD + k];
    }
    out[((size_t)b * TT + t) * JJ + j] = s + ct + qt;
}

extern "C" void kernel_launch(void* const* d_in, const int* in_sizes, int n_in,
                              void* d_out, int out_size, void* d_ws, size_t ws_size,
                              hipStream_t stream) {
    (void)in_sizes; (void)n_in; (void)out_size;
    const float* ctx = (const float*)d_in[0];
    const float* que = (const float*)d_in[1];
    const float* wv  = (const float*)d_in[2];
    float* out = (float*)d_out;

    if (ws_size < WS_NEED) {
        naive_kernel<<<dim3(JJ / 16, TT / 16, NB), dim3(256), 0, stream>>>(ctx, que, wv, out);
        return;
    }

    __bf16* ctxb = (__bf16*)d_ws;
    __bf16* queb = (__bf16*)((char*)d_ws + WS_QUEB);
    float*  cterm = (float*)((char*)d_ws + WS_CTERM);
    float*  qterm = (float*)((char*)d_ws + WS_QTERM);

    prep_kernel<<<dim3(2048), dim3(256), 0, stream>>>(ctx, que, wv, ctxb, queb, cterm, qterm);
    gemm_kernel<<<dim3(2048), dim3(256), 0, stream>>>(ctxb, queb, cterm, qterm, out);
}

// Round 11
// 71.787 us; speedup vs baseline: 1.3536x; 1.3536x over previous
//
#include <hip/hip_runtime.h>
#include <stdint.h>

typedef __bf16 bf16x8 __attribute__((ext_vector_type(8)));
typedef float  f32x4  __attribute__((ext_vector_type(4)));

typedef __attribute__((address_space(1))) const void g_void;
typedef __attribute__((address_space(3))) void l_void;

constexpr int NB = 32, TT = 2048, JJ = 512, DD = 256;

// d_ws: queb bf16[32][512][256] = 8388608 B ; qterm f32[32][512] = 65536 B
constexpr size_t WS_QTERM = 8388608;
constexpr size_t WS_NEED  = 8454144;

// ============ kernel 1: que*wm -> bf16, que.wq -> qterm (12.6 MB) ===========
__global__ __launch_bounds__(256)
void qprep_kernel(const float* __restrict__ que, const float* __restrict__ wvec,
                  __bf16* __restrict__ queb, float* __restrict__ qterm)
{
    const int tid = threadIdx.x;
    const int colg = tid & 31, rloc = tid >> 5;
    const int k0 = colg * 8;
    const f32x4 wq0 = *(const f32x4*)(wvec + DD + k0);
    const f32x4 wq1 = *(const f32x4*)(wvec + DD + k0 + 4);
    const f32x4 wm0 = *(const f32x4*)(wvec + 2 * DD + k0);
    const f32x4 wm1 = *(const f32x4*)(wvec + 2 * DD + k0 + 4);
    #pragma unroll
    for (int i = 0; i < 4; ++i) {
        const int r = blockIdx.x * 32 + i * 8 + rloc;       // 512 blocks x 32 rows
        const float* src = que + (size_t)r * DD + k0;
        const f32x4 x0 = *(const f32x4*)src;
        const f32x4 x1 = *(const f32x4*)(src + 4);
        float d = x0[0]*wq0[0] + x0[1]*wq0[1] + x0[2]*wq0[2] + x0[3]*wq0[3]
                + x1[0]*wq1[0] + x1[1]*wq1[1] + x1[2]*wq1[2] + x1[3]*wq1[3];
        d += __shfl_xor(d, 1);  d += __shfl_xor(d, 2);  d += __shfl_xor(d, 4);
        d += __shfl_xor(d, 8);  d += __shfl_xor(d, 16);
        bf16x8 pk;
        #pragma unroll
        for (int j = 0; j < 4; ++j) {
            pk[j]     = (__bf16)(x0[j] * wm0[j]);   // wm folded into B side
            pk[4 + j] = (__bf16)(x1[j] * wm1[j]);
        }
        *(bf16x8*)(queb + (size_t)r * DD + k0) = pk;
        if (colg == 0) qterm[r] = d;
    }
}

// ============ kernel 2: fused ctx-cvt + MFMA GEMM + epilogue ================
// LDS: sA [0,16K) bf16[128][64] (128B rows, slot s of row r at s^(r&7));
//      sB0 [16K,32K), sB1 [32K,48K) same layout; wc_s [48K+1K); c_s 512 B.
// A: ctx f32 read once per block, cvt once, cterm fused. B: queb DMA dbuf.
__global__ __launch_bounds__(256)
void main_kernel(const float* __restrict__ ctx, const float* __restrict__ wvec,
                 const __bf16* __restrict__ queb, const float* __restrict__ qterm,
                 float* __restrict__ out)
{
    __shared__ __align__(1024) unsigned char lds[50688];
    float* wc_s = (float*)(lds + 49152);
    float* c_s  = (float*)(lds + 50176);

    const int tid = threadIdx.x;
    const int l = tid & 63, wid = tid >> 6;

    // XCD swizzle: 2048 blocks, 256 consecutive ids per XCD (4 whole batches)
    const int pb = blockIdx.x;
    const int id = (pb & 7) * 256 + (pb >> 3);
    const int n0 = (id & 3) * 128;
    const int m0 = ((id >> 2) & 15) * 128;
    const int bI = id >> 6;

    if (tid < 64) *(f32x4*)(wc_s + tid * 4) = *(const f32x4*)(wvec + tid * 4);

    // A staging: thread -> row tid>>1, half tid&1 (32 f32 per step)
    const int arow = tid >> 1, ahalf = tid & 1;
    const float* aSrc = ctx + ((size_t)bI * TT + m0 + arow) * DD + ahalf * 32;

    // B staging DMA (R8-proven): wave wid covers rows [wid*32,+32), 4 issues
    const int brow = wid * 32 + (l >> 3);
    const int bsl  = ((l & 7) ^ ((l >> 3) & 7)) << 3;   // pre-swizzled source slot
    const __bf16* bSrc = queb + ((size_t)bI * JJ + n0 + brow) * DD + bsl;
    unsigned char* bDst = lds + 16384 + wid * 4096;

    auto stageB = [&](int k, int buf) {
        #pragma unroll
        for (int j = 0; j < 4; ++j)
            __builtin_amdgcn_global_load_lds((g_void*)(bSrc + (size_t)j * 8 * DD + k * 64),
                                             (l_void*)(bDst + buf * 16384 + j * 1024), 16, 0, 0);
    };

    f32x4 a[8];
    auto loadA = [&](int k) {
        #pragma unroll
        for (int c = 0; c < 8; ++c) a[c] = *(const f32x4*)(aSrc + k * 64 + c * 4);
    };

    // prologue: B(0) -> A(0) -> B(1): cvt(0)'s auto-wait drains thru A(0),
    // leaving B(1) in flight.
    stageB(0, 0);
    loadA(0);
    stageB(1, 1);
    asm volatile("s_waitcnt lgkmcnt(0)" ::: "memory");   // wc_s writes retired
    __builtin_amdgcn_s_barrier();                        // wc_s visible to all

    f32x4 acc[4][4];
    #pragma unroll
    for (int m = 0; m < 4; ++m)
        #pragma unroll
        for (int n = 0; n < 4; ++n) acc[m][n] = f32x4{0.f, 0.f, 0.f, 0.f};

    const int wm_0 = (wid >> 1) * 64;
    const int wn_0 = (wid & 1) * 64;
    const int lr = l & 15, hi = l >> 4;

    float cp = 0.f;
    unsigned char* aWr = lds + arow * 128;
    const int asw = arow & 7;

    #pragma unroll
    for (int k = 0; k < 4; ++k) {
        // ---- cvt + cterm (uses A(k) regs: compiler vmcnt-waits, landing B(k) too)
        bf16x8 pa[4];
        {
            const float* wcp = wc_s + k * 64 + ahalf * 32;
            #pragma unroll
            for (int c2 = 0; c2 < 4; ++c2) {
                const f32x4 w0 = *(const f32x4*)(wcp + c2 * 8);
                const f32x4 w1 = *(const f32x4*)(wcp + c2 * 8 + 4);
                #pragma unroll
                for (int j = 0; j < 4; ++j) {
                    pa[c2][j]     = (__bf16)a[c2 * 2][j];
                    pa[c2][4 + j] = (__bf16)a[c2 * 2 + 1][j];
                    cp += a[c2 * 2][j] * w0[j] + a[c2 * 2 + 1][j] * w1[j];
                }
            }
        }
        __builtin_amdgcn_s_barrier();                    // readers of step k-1 done

        #pragma unroll
        for (int c2 = 0; c2 < 4; ++c2)
            *(bf16x8*)(aWr + (((ahalf * 4 + c2) ^ asw) << 4)) = pa[c2];

        if (k >= 1 && k < 3) stageB(k + 1, (k + 1) & 1); // refill just-freed buf
        if (k < 3) loadA(k + 1);                         // flight ~1 step

        asm volatile("s_waitcnt lgkmcnt(0)" ::: "memory");   // ds_writes retired
        __builtin_amdgcn_sched_barrier(0);
        __builtin_amdgcn_s_barrier();                    // tile k fully in LDS

        const unsigned char* bBuf = lds + 16384 + (k & 1) * 16384;
        bf16x8 af[2][4], bf[2][4];
        #pragma unroll
        for (int kk = 0; kk < 2; ++kk) {
            const int c = kk * 4 + hi;
            #pragma unroll
            for (int m = 0; m < 4; ++m) {
                const int r = wm_0 + m * 16 + lr;
                af[kk][m] = *(const bf16x8*)(lds + r * 128 + ((c ^ (r & 7)) << 4));
            }
            #pragma unroll
            for (int n = 0; n < 4; ++n) {
                const int r = wn_0 + n * 16 + lr;
                bf[kk][n] = *(const bf16x8*)(bBuf + r * 128 + ((c ^ (r & 7)) << 4));
            }
        }
        __builtin_amdgcn_s_setprio(1);
        #pragma unroll
        for (int kk = 0; kk < 2; ++kk)
            #pragma unroll
            for (int m = 0; m < 4; ++m)
                #pragma unroll
                for (int n = 0; n < 4; ++n)
                    acc[m][n] = __builtin_amdgcn_mfma_f32_16x16x32_bf16(bf[kk][n], af[kk][m],
                                                                        acc[m][n], 0, 0, 0);
        __builtin_amdgcn_s_setprio(0);
    }

    // cterm: pair-reduce (threads 2r,2r+1), park in LDS
    cp += __shfl_xor(cp, 1);
    if (ahalf == 0) c_s[arow] = cp;
    __syncthreads();

    // epilogue (R7-verified): out[t=wm_0+m*16+lr][j=wn_0+n*16+hi*4+q]
    const int jb = wn_0 + hi * 4;
    #pragma unroll
    for (int m = 0; m < 4; ++m) {
        const int rowL = wm_0 + m * 16 + lr;
        const float cv = c_s[rowL];
        float* rowp = out + ((size_t)bI * TT + m0 + rowL) * JJ + n0;
        #pragma unroll
        for (int n = 0; n < 4; ++n) {
            const int colL = jb + n * 16;
            const f32x4 qv = *(const f32x4*)(qterm + (size_t)bI * JJ + n0 + colL);
            const f32x4 v = acc[m][n];
            f32x4 w = {v[0] + cv + qv[0], v[1] + cv + qv[1],
                       v[2] + cv + qv[2], v[3] + cv + qv[3]};
            *(f32x4*)(rowp + colL) = w;
        }
    }
}

// ================= fallback (only if ws too small; correctness-only) ========
__global__ __launch_bounds__(256)
void naive_kernel(const float* __restrict__ ctx, const float* __restrict__ que,
                  const float* __restrict__ wvec, float* __restrict__ out)
{
    const int j = blockIdx.x * 16 + (threadIdx.x & 15);
    const int t = blockIdx.y * 16 + (threadIdx.x >> 4);
    const int b = blockIdx.z;
    const float* cr = ctx + ((size_t)b * TT + t) * DD;
    const float* qr = que + ((size_t)b * JJ + j) * DD;
    float s = 0.f, ct = 0.f, qt = 0.f;
    for (int k = 0; k < DD; ++k) {
        const float cv = cr[k], qv = qr[k];
        s  += cv * wvec[2 * DD + k] * qv;
        ct += cv * wvec[k];
        qt += qv * wvec[DD + k];
    }
    out[((size_t)b * TT + t) * JJ + j] = s + ct + qt;
}

extern "C" void kernel_launch(void* const* d_in, const int* in_sizes, int n_in,
                              void* d_out, int out_size, void* d_ws, size_t ws_size,
                              hipStream_t stream) {
    (void)in_sizes; (void)n_in; (void)out_size;
    const float* ctx = (const float*)d_in[0];
    const float* que = (const float*)d_in[1];
    const float* wv  = (const float*)d_in[2];
    float* out = (float*)d_out;

    if (ws_size < WS_NEED) {
        naive_kernel<<<dim3(JJ / 16, TT / 16, NB), dim3(256), 0, stream>>>(ctx, que, wv, out);
        return;
    }

    __bf16* queb  = (__bf16*)d_ws;
    float*  qterm = (float*)((char*)d_ws + WS_QTERM);

    qprep_kernel<<<dim3(512), dim3(256), 0, stream>>>(que, wv, queb, qterm);
    main_kernel<<<dim3(2048), dim3(256), 0, stream>>>(ctx, wv, queb, qterm, out);
}

// Round 12
// 56.625 us; speedup vs baseline: 1.7160x; 1.2677x over previous
//
#include <hip/hip_runtime.h>
#include <stdint.h>

typedef __bf16 bf16x8 __attribute__((ext_vector_type(8)));
typedef float  f32x4  __attribute__((ext_vector_type(4)));

typedef __attribute__((address_space(1))) const void g_void;
typedef __attribute__((address_space(3))) void l_void;

constexpr int NB = 32, TT = 2048, JJ = 512, DD = 256;
constexpr int CTX_ROWS = NB * TT;                 // 65536
constexpr int QUE_ROWS = NB * JJ;                 // 16384
constexpr int ALL_ROWS = CTX_ROWS + QUE_ROWS;     // 81920

// d_ws layout (bytes):
//   ctxb  [0,        33554432)   bf16[32][2048][256]
//   queb  [33554432, 41943040)   bf16[32][512][256]
//   cterm [41943040, 42205184)   f32[32][2048]
//   qterm [42205184, 42270720)   f32[32][512]
constexpr size_t WS_QUEB  = 33554432;
constexpr size_t WS_CTERM = 41943040;
constexpr size_t WS_QTERM = 42205184;
constexpr size_t WS_NEED  = 42270720;

// ================= kernel 1: convert + term dots (memory-bound) =============
__global__ __launch_bounds__(256)
void prep_kernel(const float* __restrict__ ctx, const float* __restrict__ que,
                 const float* __restrict__ wvec,
                 __bf16* __restrict__ ctxb, __bf16* __restrict__ queb,
                 float* __restrict__ cterm, float* __restrict__ qterm)
{
    const int tid  = threadIdx.x;
    const int colg = tid & 31;        // 32 col-groups x 8 f32 = 256
    const int rloc = tid >> 5;        // 8 rows per block
    const int k0   = colg * 8;

    const f32x4 wc0 = *(const f32x4*)(wvec + k0);
    const f32x4 wc1 = *(const f32x4*)(wvec + k0 + 4);
    const f32x4 wq0 = *(const f32x4*)(wvec + DD + k0);
    const f32x4 wq1 = *(const f32x4*)(wvec + DD + k0 + 4);
    const f32x4 wm0 = *(const f32x4*)(wvec + 2 * DD + k0);
    const f32x4 wm1 = *(const f32x4*)(wvec + 2 * DD + k0 + 4);

    for (int r = blockIdx.x * 8 + rloc; r < ALL_ROWS; r += gridDim.x * 8) {
        const bool isC = (r < CTX_ROWS);
        const int  rr  = isC ? r : (r - CTX_ROWS);
        const float* src = (isC ? ctx : que) + (size_t)rr * DD + k0;
        const f32x4 x0 = *(const f32x4*)src;
        const f32x4 x1 = *(const f32x4*)(src + 4);

        const f32x4 wd0 = isC ? wc0 : wq0;
        const f32x4 wd1 = isC ? wc1 : wq1;
        float d = x0[0]*wd0[0] + x0[1]*wd0[1] + x0[2]*wd0[2] + x0[3]*wd0[3]
                + x1[0]*wd1[0] + x1[1]*wd1[1] + x1[2]*wd1[2] + x1[3]*wd1[3];
        d += __shfl_xor(d, 1);  d += __shfl_xor(d, 2);  d += __shfl_xor(d, 4);
        d += __shfl_xor(d, 8);  d += __shfl_xor(d, 16);

        bf16x8 pk;
        #pragma unroll
        for (int j = 0; j < 4; ++j) {
            pk[j]     = (__bf16)(isC ? x0[j] * wm0[j] : x0[j]);
            pk[4 + j] = (__bf16)(isC ? x1[j] * wm1[j] : x1[j]);
        }
        *(bf16x8*)((isC ? ctxb : queb) + (size_t)rr * DD + k0) = pk;
        if (colg == 0) (isC ? cterm : qterm)[rr] = d;
    }
}

// ================= kernel 2: bf16 MFMA GEMM + term epilogue ==================
// LDS: sA bf16[128][64] @0 (16KB), sB @16384 (16KB). 16B chunk c of row r at
// slot c^(r&7) (conflict-free ds_read_b128); DMA writes linearly, source
// address carries the inverse permutation (m173 pattern).
__global__ __launch_bounds__(256)
void gemm_kernel(const __bf16* __restrict__ ctxb, const __bf16* __restrict__ queb,
                 const float* __restrict__ cterm, const float* __restrict__ qterm,
                 float* __restrict__ out)
{
    __shared__ __align__(1024) unsigned char lds[32768];

    const int tid = threadIdx.x;
    const int l   = tid & 63;
    const int wid = tid >> 6;

    // XCD-aware swizzle: each XCD gets 256 consecutive work-ids (4 batches).
    const int pb = blockIdx.x;
    const int id = (pb & 7) * 256 + (pb >> 3);
    const int n0 = (id & 3) * 128;
    const int m0 = ((id >> 2) & 15) * 128;
    const int bI = id >> 6;

    // --- DMA staging: per wave, 4 issues/matrix; issue j covers rows wid*32+j*8..+8
    const int lrow8 = l >> 3;                 // 0..7
    const int lslot = l & 7;
    const int srcsw = (lslot ^ lrow8) << 3;   // swizzled chunk, element offset

    const __bf16* aBase = ctxb + ((size_t)bI * TT + m0 + wid * 32 + lrow8) * DD + srcsw;
    const __bf16* bBase = queb + ((size_t)bI * JJ + n0 + wid * 32 + lrow8) * DD + srcsw;
    unsigned char* ldsA = lds + wid * 4096;
    unsigned char* ldsB = lds + 16384 + wid * 4096;

    auto stage = [&](int k) {
        #pragma unroll
        for (int j = 0; j < 4; ++j) {
            __builtin_amdgcn_global_load_lds((g_void*)(aBase + (size_t)j * 8 * DD + k * 64),
                                             (l_void*)(ldsA + j * 1024), 16, 0, 0);
            __builtin_amdgcn_global_load_lds((g_void*)(bBase + (size_t)j * 8 * DD + k * 64),
                                             (l_void*)(ldsB + j * 1024), 16, 0, 0);
        }
    };

    stage(0);

    f32x4 acc[4][4];
    #pragma unroll
    for (int m = 0; m < 4; ++m)
        #pragma unroll
        for (int n = 0; n < 4; ++n) acc[m][n] = f32x4{0.f, 0.f, 0.f, 0.f};

    const int wm_0 = (wid >> 1) * 64;
    const int wn_0 = (wid & 1) * 64;
    const int lr = l & 15;
    const int hi = l >> 4;

    #pragma unroll
    for (int k = 0; k < 4; ++k) {
        asm volatile("s_waitcnt vmcnt(0)" ::: "memory");   // tile k DMA done
        __builtin_amdgcn_s_barrier();                      // everyone's done

        bf16x8 af[2][4], bfr[2][4];
        #pragma unroll
        for (int kk = 0; kk < 2; ++kk) {
            const int c = kk * 4 + hi;
            #pragma unroll
            for (int m = 0; m < 4; ++m) {
                const int r = wm_0 + m * 16 + lr;
                af[kk][m] = *(const bf16x8*)(lds + r * 128 + ((c ^ (r & 7)) << 4));
            }
            #pragma unroll
            for (int n = 0; n < 4; ++n) {
                const int r = wn_0 + n * 16 + lr;
                bfr[kk][n] = *(const bf16x8*)(lds + 16384 + r * 128 + ((c ^ (r & 7)) << 4));
            }
        }
        asm volatile("s_waitcnt lgkmcnt(0)" ::: "memory"); // frag reads retired
        __builtin_amdgcn_sched_barrier(0);
        __builtin_amdgcn_s_barrier();                      // safe to overwrite tile
        if (k < 3) stage(k + 1);                           // DMA flight ∥ MFMA below

        __builtin_amdgcn_s_setprio(1);
        #pragma unroll
        for (int kk = 0; kk < 2; ++kk)
            #pragma unroll
            for (int m = 0; m < 4; ++m)
                #pragma unroll
                for (int n = 0; n < 4; ++n)
                    acc[m][n] = __builtin_amdgcn_mfma_f32_16x16x32_bf16(af[kk][m], bfr[kk][n],
                                                                        acc[m][n], 0, 0, 0);
        __builtin_amdgcn_s_setprio(0);
    }

    // --- epilogue: D mapping col=l&15, row=hi*4+q; terms straight from global (L2-hot)
    const int lq = hi * 4;
    #pragma unroll
    for (int m = 0; m < 4; ++m) {
        const int rowL = wm_0 + m * 16 + lq;
        const f32x4 cv = *(const f32x4*)(cterm + (size_t)bI * TT + m0 + rowL);
        #pragma unroll
        for (int n = 0; n < 4; ++n) {
            const int colL = wn_0 + n * 16 + lr;
            const float qv = qterm[(size_t)bI * JJ + n0 + colL];
            float* dst = out + ((size_t)bI * TT + m0 + rowL) * JJ + (n0 + colL);
            const f32x4 v = acc[m][n];
            #pragma unroll
            for (int q = 0; q < 4; ++q)
                dst[(size_t)q * JJ] = v[q] + cv[q] + qv;
        }
    }
}

// ================= fallback (only if ws too small; correctness-only) ========
__global__ __launch_bounds__(256)
void naive_kernel(const float* __restrict__ ctx, const float* __restrict__ que,
                  const float* __restrict__ wvec, float* __restrict__ out)
{
    const int j = blockIdx.x * 16 + (threadIdx.x & 15);
    const int t = blockIdx.y * 16 + (threadIdx.x >> 4);
    const int b = blockIdx.z;
    const float* cr = ctx + ((size_t)b * TT + t) * DD;
    const float* qr = que + ((size_t)b * JJ + j) * DD;
    float s = 0.f, ct = 0.f, qt = 0.f;
    for (int k = 0; k < DD; ++k) {
        const float cv = cr[k], qv = qr[k];
        s  += cv * wvec[2 * DD + k] * qv;
        ct += cv * wvec[k];
        qt += qv * wvec[DD + k];
    }
    out[((size_t)b * TT + t) * JJ + j] = s + ct + qt;
}

extern "C" void kernel_launch(void* const* d_in, const int* in_sizes, int n_in,
                              void* d_out, int out_size, void* d_ws, size_t ws_size,
                              hipStream_t stream) {
    (void)in_sizes; (void)n_in; (void)out_size;
    const float* ctx = (const float*)d_in[0];
    const float* que = (const float*)d_in[1];
    const float* wv  = (const float*)d_in[2];
    float* out = (float*)d_out;

    if (ws_size < WS_NEED) {
        naive_kernel<<<dim3(JJ / 16, TT / 16, NB), dim3(256), 0, stream>>>(ctx, que, wv, out);
        return;
    }

    __bf16* ctxb = (__bf16*)d_ws;
    __bf16* queb = (__bf16*)((char*)d_ws + WS_QUEB);
    float*  cterm = (float*)((char*)d_ws + WS_CTERM);
    float*  qterm = (float*)((char*)d_ws + WS_QTERM);

    prep_kernel<<<dim3(2048), dim3(256), 0, stream>>>(ctx, que, wv, ctxb, queb, cterm, qterm);
    gemm_kernel<<<dim3(2048), dim3(256), 0, stream>>>(ctxb, queb, cterm, qterm, out);
}

// Round 13
// 55.081 us; speedup vs baseline: 1.7641x; 1.0280x over previous
//
#include <hip/hip_runtime.h>
#include <stdint.h>

typedef __bf16 bf16x8 __attribute__((ext_vector_type(8)));
typedef float  f32x4  __attribute__((ext_vector_type(4)));

typedef __attribute__((address_space(1))) const void g_void;
typedef __attribute__((address_space(3))) void l_void;

constexpr int NB = 32, TT = 2048, JJ = 512, DD = 256;

// d_ws layout (bytes):
//   ctxb  [0,        33554432)   bf16[32][2048][256]
//   queb  [33554432, 41943040)   bf16[32][512][256]
//   cterm [41943040, 42205184)   f32[32][2048]
//   qterm [42205184, 42270720)   f32[32][512]
constexpr size_t WS_QUEB  = 33554432;
constexpr size_t WS_CTERM = 41943040;
constexpr size_t WS_QTERM = 42205184;
constexpr size_t WS_NEED  = 42270720;

// ================= kernel 1: convert + term dots, XCD-aligned ===============
// Block p (XCD = p&7 under round-robin dispatch — same assumption as gemm's
// swizzle) preps exactly the batches [4*xcd, 4*xcd+4) that gemm blocks on
// that XCD consume: iters 0-3 = ctx batches, iter 4 = the 4 que batches.
// Cross-kernel L2 carry: ws lines are written and read on the same XCD L2.
__global__ __launch_bounds__(256)
void prep_kernel(const float* __restrict__ ctx, const float* __restrict__ que,
                 const float* __restrict__ wvec,
                 __bf16* __restrict__ ctxb, __bf16* __restrict__ queb,
                 float* __restrict__ cterm, float* __restrict__ qterm)
{
    const int tid  = threadIdx.x;
    const int colg = tid & 31;        // 32 col-groups x 8 f32 = 256
    const int rloc = tid >> 5;        // 8 rows per block-iter
    const int k0   = colg * 8;

    const int pb    = blockIdx.x;     // 2048 blocks
    const int xcd   = pb & 7;
    const int local = pb >> 3;        // 0..255
    const int b0    = xcd * 4;

    const f32x4 wc0 = *(const f32x4*)(wvec + k0);
    const f32x4 wc1 = *(const f32x4*)(wvec + k0 + 4);
    const f32x4 wq0 = *(const f32x4*)(wvec + DD + k0);
    const f32x4 wq1 = *(const f32x4*)(wvec + DD + k0 + 4);
    const f32x4 wm0 = *(const f32x4*)(wvec + 2 * DD + k0);
    const f32x4 wm1 = *(const f32x4*)(wvec + 2 * DD + k0 + 4);

    // ---- iters 0-3: ctx batch b0+i, rows local*8+rloc (contiguous per block)
    #pragma unroll
    for (int i = 0; i < 4; ++i) {
        const size_t r = (size_t)(b0 + i) * TT + local * 8 + rloc;
        const float* src = ctx + r * DD + k0;
        const f32x4 x0 = *(const f32x4*)src;
        const f32x4 x1 = *(const f32x4*)(src + 4);

        float d = x0[0]*wc0[0] + x0[1]*wc0[1] + x0[2]*wc0[2] + x0[3]*wc0[3]
                + x1[0]*wc1[0] + x1[1]*wc1[1] + x1[2]*wc1[2] + x1[3]*wc1[3];
        d += __shfl_xor(d, 1);  d += __shfl_xor(d, 2);  d += __shfl_xor(d, 4);
        d += __shfl_xor(d, 8);  d += __shfl_xor(d, 16);

        bf16x8 pk;
        #pragma unroll
        for (int j = 0; j < 4; ++j) {
            pk[j]     = (__bf16)(x0[j] * wm0[j]);
            pk[4 + j] = (__bf16)(x1[j] * wm1[j]);
        }
        *(bf16x8*)(ctxb + r * DD + k0) = pk;
        if (colg == 0) cterm[r] = d;
    }

    // ---- iter 4: que rows of the same 4 batches (2048 rows per XCD-group)
    {
        const int idx = local * 8 + rloc;            // 0..2047
        const size_t r = (size_t)(b0 + (idx >> 9)) * JJ + (idx & 511);
        const float* src = que + r * DD + k0;
        const f32x4 x0 = *(const f32x4*)src;
        const f32x4 x1 = *(const f32x4*)(src + 4);

        float d = x0[0]*wq0[0] + x0[1]*wq0[1] + x0[2]*wq0[2] + x0[3]*wq0[3]
                + x1[0]*wq1[0] + x1[1]*wq1[1] + x1[2]*wq1[2] + x1[3]*wq1[3];
        d += __shfl_xor(d, 1);  d += __shfl_xor(d, 2);  d += __shfl_xor(d, 4);
        d += __shfl_xor(d, 8);  d += __shfl_xor(d, 16);

        bf16x8 pk;
        #pragma unroll
        for (int j = 0; j < 4; ++j) {
            pk[j]     = (__bf16)x0[j];
            pk[4 + j] = (__bf16)x1[j];
        }
        *(bf16x8*)(queb + r * DD + k0) = pk;
        if (colg == 0) qterm[r] = d;
    }
}

// ================= kernel 2: bf16 MFMA GEMM + term epilogue (R12, unchanged) =
// LDS: sA bf16[128][64] @0 (16KB), sB @16384 (16KB). 16B chunk c of row r at
// slot c^(r&7) (conflict-free ds_read_b128); DMA writes linearly, source
// address carries the inverse permutation (m173 pattern).
__global__ __launch_bounds__(256)
void gemm_kernel(const __bf16* __restrict__ ctxb, const __bf16* __restrict__ queb,
                 const float* __restrict__ cterm, const float* __restrict__ qterm,
                 float* __restrict__ out)
{
    __shared__ __align__(1024) unsigned char lds[32768];

    const int tid = threadIdx.x;
    const int l   = tid & 63;
    const int wid = tid >> 6;

    // XCD-aware swizzle: each XCD gets 256 consecutive work-ids (4 batches).
    const int pb = blockIdx.x;
    const int id = (pb & 7) * 256 + (pb >> 3);
    const int n0 = (id & 3) * 128;
    const int m0 = ((id >> 2) & 15) * 128;
    const int bI = id >> 6;

    // --- DMA staging: per wave, 4 issues/matrix; issue j covers rows wid*32+j*8..+8
    const int lrow8 = l >> 3;                 // 0..7
    const int lslot = l & 7;
    const int srcsw = (lslot ^ lrow8) << 3;   // swizzled chunk, element offset

    const __bf16* aBase = ctxb + ((size_t)bI * TT + m0 + wid * 32 + lrow8) * DD + srcsw;
    const __bf16* bBase = queb + ((size_t)bI * JJ + n0 + wid * 32 + lrow8) * DD + srcsw;
    unsigned char* ldsA = lds + wid * 4096;
    unsigned char* ldsB = lds + 16384 + wid * 4096;

    auto stage = [&](int k) {
        #pragma unroll
        for (int j = 0; j < 4; ++j) {
            __builtin_amdgcn_global_load_lds((g_void*)(aBase + (size_t)j * 8 * DD + k * 64),
                                             (l_void*)(ldsA + j * 1024), 16, 0, 0);
            __builtin_amdgcn_global_load_lds((g_void*)(bBase + (size_t)j * 8 * DD + k * 64),
                                             (l_void*)(ldsB + j * 1024), 16, 0, 0);
        }
    };

    stage(0);

    f32x4 acc[4][4];
    #pragma unroll
    for (int m = 0; m < 4; ++m)
        #pragma unroll
        for (int n = 0; n < 4; ++n) acc[m][n] = f32x4{0.f, 0.f, 0.f, 0.f};

    const int wm_0 = (wid >> 1) * 64;
    const int wn_0 = (wid & 1) * 64;
    const int lr = l & 15;
    const int hi = l >> 4;

    #pragma unroll
    for (int k = 0; k < 4; ++k) {
        asm volatile("s_waitcnt vmcnt(0)" ::: "memory");   // tile k DMA done
        __builtin_amdgcn_s_barrier();                      // everyone's done

        bf16x8 af[2][4], bfr[2][4];
        #pragma unroll
        for (int kk = 0; kk < 2; ++kk) {
            const int c = kk * 4 + hi;
            #pragma unroll
            for (int m = 0; m < 4; ++m) {
                const int r = wm_0 + m * 16 + lr;
                af[kk][m] = *(const bf16x8*)(lds + r * 128 + ((c ^ (r & 7)) << 4));
            }
            #pragma unroll
            for (int n = 0; n < 4; ++n) {
                const int r = wn_0 + n * 16 + lr;
                bfr[kk][n] = *(const bf16x8*)(lds + 16384 + r * 128 + ((c ^ (r & 7)) << 4));
            }
        }
        asm volatile("s_waitcnt lgkmcnt(0)" ::: "memory"); // frag reads retired
        __builtin_amdgcn_sched_barrier(0);
        __builtin_amdgcn_s_barrier();                      // safe to overwrite tile
        if (k < 3) stage(k + 1);                           // DMA flight ∥ MFMA below

        __builtin_amdgcn_s_setprio(1);
        #pragma unroll
        for (int kk = 0; kk < 2; ++kk)
            #pragma unroll
            for (int m = 0; m < 4; ++m)
                #pragma unroll
                for (int n = 0; n < 4; ++n)
                    acc[m][n] = __builtin_amdgcn_mfma_f32_16x16x32_bf16(af[kk][m], bfr[kk][n],
                                                                        acc[m][n], 0, 0, 0);
        __builtin_amdgcn_s_setprio(0);
    }

    // --- epilogue: D mapping col=l&15, row=hi*4+q; terms straight from global (L2-hot)
    const int lq = hi * 4;
    #pragma unroll
    for (int m = 0; m < 4; ++m) {
        const int rowL = wm_0 + m * 16 + lq;
        const f32x4 cv = *(const f32x4*)(cterm + (size_t)bI * TT + m0 + rowL);
        #pragma unroll
        for (int n = 0; n < 4; ++n) {
            const int colL = wn_0 + n * 16 + lr;
            const float qv = qterm[(size_t)bI * JJ + n0 + colL];
            float* dst = out + ((size_t)bI * TT + m0 + rowL) * JJ + (n0 + colL);
            const f32x4 v = acc[m][n];
            #pragma unroll
            for (int q = 0; q < 4; ++q)
                dst[(size_t)q * JJ] = v[q] + cv[q] + qv;
        }
    }
}

// ================= fallback (only if ws too small; correctness-only) ========
__global__ __launch_bounds__(256)
void naive_kernel(const float* __restrict__ ctx, const float* __restrict__ que,
                  const float* __restrict__ wvec, float* __restrict__ out)
{
    const int j = blockIdx.x * 16 + (threadIdx.x & 15);
    const int t = blockIdx.y * 16 + (threadIdx.x >> 4);
    const int b = blockIdx.z;
    const float* cr = ctx + ((size_t)b * TT + t) * DD;
    const float* qr = que + ((size_t)b * JJ + j) * DD;
    float s = 0.f, ct = 0.f, qt = 0.f;
    for (int k = 0; k < DD; ++k) {
        const float cv = cr[k], qv = qr[k];
        s  += cv * wvec[2 * DD + k] * qv;
        ct += cv * wvec[k];
        qt += qv * wvec[DD + k];
    }
    out[((size_t)b * TT + t) * JJ + j] = s + ct + qt;
}

extern "C" void kernel_launch(void* const* d_in, const int* in_sizes, int n_in,
                              void* d_out, int out_size, void* d_ws, size_t ws_size,
                              hipStream_t stream) {
    (void)in_sizes; (void)n_in; (void)out_size;
    const float* ctx = (const float*)d_in[0];
    const float* que = (const float*)d_in[1];
    const float* wv  = (const float*)d_in[2];
    float* out = (float*)d_out;

    if (ws_size < WS_NEED) {
        naive_kernel<<<dim3(JJ / 16, TT / 16, NB), dim3(256), 0, stream>>>(ctx, que, wv, out);
        return;
    }

    __bf16* ctxb = (__bf16*)d_ws;
    __bf16* queb = (__bf16*)((char*)d_ws + WS_QUEB);
    float*  cterm = (float*)((char*)d_ws + WS_CTERM);
    float*  qterm = (float*)((char*)d_ws + WS_QTERM);

    prep_kernel<<<dim3(2048), dim3(256), 0, stream>>>(ctx, que, wv, ctxb, queb, cterm, qterm);
    gemm_kernel<<<dim3(2048), dim3(256), 0, stream>>>(ctxb, queb, cterm, qterm, out);
}